// Round 4
// baseline (1250.799 us; speedup 1.0000x reference)
//
#include <hip/hip_runtime.h>
#include <hip/hip_bf16.h>

#define NN 100000
#define EE 1000000
#define NCH 15625          // EE / 64 exactly
#define NBLK 512           // 2 persistent blocks per CU

typedef short bf16x8 __attribute__((ext_vector_type(8)));
typedef float f32x4 __attribute__((ext_vector_type(4)));

__device__ __forceinline__ unsigned short f2bf_rne(float f) {
    unsigned int u = __builtin_bit_cast(unsigned int, f);
    u = u + 0x7fffu + ((u >> 16) & 1u);
    return (unsigned short)(u >> 16);
}

// product of two bf16 pairs (packed dwords) -> bf16 pair (truncation)
__device__ __forceinline__ unsigned int bfprod2(unsigned int a, unsigned int b) {
    float alo = __builtin_bit_cast(float, a << 16);
    float ahi = __builtin_bit_cast(float, a & 0xffff0000u);
    float blo = __builtin_bit_cast(float, b << 16);
    float bhi = __builtin_bit_cast(float, b & 0xffff0000u);
    unsigned int lo = __builtin_bit_cast(unsigned int, alo * blo);
    unsigned int hi = __builtin_bit_cast(unsigned int, ahi * bhi);
    return __builtin_amdgcn_perm(hi, lo, 0x07060302u);
}

__device__ __forceinline__ unsigned int packtrunc(float lo, float hi) {
    return __builtin_amdgcn_perm(__builtin_bit_cast(unsigned int, hi),
                                 __builtin_bit_cast(unsigned int, lo), 0x07060302u);
}

template<int CTRL>
__device__ __forceinline__ float dpp_add(float v) {
    int s = __builtin_bit_cast(int, v);
    int m = __builtin_amdgcn_mov_dpp(s, CTRL, 0xF, 0xF, true);
    return v + __builtin_bit_cast(float, m);
}
__device__ __forceinline__ float red16(float v) {   // sum over 16-lane row (VALU pipe)
    v = dpp_add<0xB1>(v);
    v = dpp_add<0x4E>(v);
    v = dpp_add<0x124>(v);
    v = dpp_add<0x128>(v);
    return v;
}

// W1 [k][c] f32 -> W1T [c][k] bf16
__global__ void k_w1t(const float* __restrict__ W1, unsigned short* __restrict__ w1t) {
    int c = blockIdx.x, k = threadIdx.x;
    w1t[c * 256 + k] = f2bf_rne(W1[k * 256 + c]);
}

__global__ void k_zconv(const float* __restrict__ z, unsigned short* __restrict__ z16) {
    long long i = ((long long)blockIdx.x * 256 + threadIdx.x) * 8;
    float4 a = *(const float4*)(z + i);
    float4 b = *(const float4*)(z + i + 4);
    uint4 o;
    o.x = (unsigned)f2bf_rne(a.x) | ((unsigned)f2bf_rne(a.y) << 16);
    o.y = (unsigned)f2bf_rne(a.z) | ((unsigned)f2bf_rne(a.w) << 16);
    o.z = (unsigned)f2bf_rne(b.x) | ((unsigned)f2bf_rne(b.y) << 16);
    o.w = (unsigned)f2bf_rne(b.z) | ((unsigned)f2bf_rne(b.w) << 16);
    *(uint4*)(z16 + i) = o;
}

// Persistent fused kernel: 512 blocks (2/CU) x 512 threads (8 waves: 2M x 4N).
// B (W1T 64-col slice, full K) pinned in VGPRs for the whole kernel.
// x tile stored in LDS directly in MFMA A-fragment order:
//   frag(mt,kk) base = (mt*8+kk)*1024 ; data for A-lane-position pos stored at
//   slot = pos ^ kk (16 B units). Reads: lane reads slot (lane^kk) -> each
//   16-lane quarter covers 2 full 128-B LDS rows (conflict-free). Writes:
//   thread (el=t>>3, q=t&7) writes pos = i*16 + (el&15) into frag kk=q ->
//   2-way balanced per quarter (free).
template<bool Z16>
__global__ __launch_bounds__(512, 4)
void k_main(const float* __restrict__ zf,
            const unsigned short* __restrict__ z16,
            const int* __restrict__ src, const int* __restrict__ dst,
            const unsigned short* __restrict__ w1t,
            const float* __restrict__ b1, const float* __restrict__ w2,
            const float* __restrict__ b2p, float* __restrict__ out)
{
    __shared__ __align__(16) char xs[2][32 * 1024];    // 2 x 32 KB frag buffers
    __shared__ float part[2][4][64];                   // 2 KB

    const int t = threadIdx.x;
    const int lane = t & 63;
    const int w = t >> 6;
    const int wm = w >> 2, wn = w & 3;      // M-half, N-quarter
    const int lr = lane & 15, lg = lane >> 4;

    // ---- B: wave's 64 W1T cols, full K=256, held in registers for the whole kernel ----
    bf16x8 B[4][8];
    float b1r[4], w2r[4];
    #pragma unroll
    for (int n = 0; n < 4; ++n) {
        const int col = wn * 64 + n * 16 + lr;
        const short* rp = (const short*)w1t + col * 256 + lg * 8;
        #pragma unroll
        for (int kk = 0; kk < 8; ++kk)
            B[n][kk] = *(const bf16x8*)(rp + kk * 32);
        b1r[n] = b1[col];
        w2r[n] = w2[col];
    }
    // pin: forbid the compiler from sinking/rematerializing the B loads
    #pragma unroll
    for (int n = 0; n < 4; ++n)
        #pragma unroll
        for (int kk = 0; kk < 8; ++kk)
            asm volatile("" : "+v"(B[n][kk]));

    const float b2s = b2p[0];
    const int el = t >> 3, q = t & 7;       // 8 threads/edge, 32 ch each (coalesced gather)
    const int mtw = el >> 4, lrw = el & 15; // writer frag coords

    uint4 ga[4], gb[4];                     // staged gather regs (bf16 path)

    auto stage_load = [&](int c) {          // issue gathers (consumed in product_store)
        const int e = c * 64 + el;
        const int s = src[e], d = dst[e];
        const uint4* sp = (const uint4*)(z16 + s * 256 + q * 32);
        const uint4* dp = (const uint4*)(z16 + d * 256 + q * 32);
        ga[0] = sp[0]; ga[1] = sp[1]; ga[2] = sp[2]; ga[3] = sp[3];
        gb[0] = dp[0]; gb[1] = dp[1]; gb[2] = dp[2]; gb[3] = dp[3];
    };
    auto product_store = [&](int p) {
        char* fb = xs[p] + (mtw * 8 + q) * 1024;
        #pragma unroll
        for (int i = 0; i < 4; ++i) {
            uint4 x;
            x.x = bfprod2(ga[i].x, gb[i].x);
            x.y = bfprod2(ga[i].y, gb[i].y);
            x.z = bfprod2(ga[i].z, gb[i].z);
            x.w = bfprod2(ga[i].w, gb[i].w);
            *(uint4*)(fb + (((i * 16 + lrw) ^ q) * 16)) = x;
        }
    };
    auto stage_f32 = [&](int c, int p) {    // f32 fallback: load+product+store
        const int e = c * 64 + el;
        const int s = src[e], d = dst[e];
        const float4* sp = (const float4*)(zf + s * 256 + q * 32);
        const float4* dp = (const float4*)(zf + d * 256 + q * 32);
        char* fb = xs[p] + (mtw * 8 + q) * 1024;
        #pragma unroll
        for (int i = 0; i < 4; ++i) {
            float4 a0 = sp[2 * i], a1 = sp[2 * i + 1];
            float4 c0 = dp[2 * i], c1 = dp[2 * i + 1];
            uint4 x;
            x.x = packtrunc(a0.x * c0.x, a0.y * c0.y);
            x.y = packtrunc(a0.z * c0.z, a0.w * c0.w);
            x.z = packtrunc(a1.x * c1.x, a1.y * c1.y);
            x.w = packtrunc(a1.z * c1.z, a1.w * c1.w);
            *(uint4*)(fb + (((i * 16 + lrw) ^ q) * 16)) = x;
        }
    };
    auto compute = [&](int p) {
        #pragma unroll
        for (int mi = 0; mi < 2; ++mi) {
            const int mt = wm * 2 + mi;
            const char* fp = xs[p] + mt * 8192;
            bf16x8 A[8];
            #pragma unroll
            for (int kk = 0; kk < 8; ++kk)
                A[kk] = *(const bf16x8*)(fp + kk * 1024 + ((lane ^ kk) * 16));
            f32x4 acc[4];
            #pragma unroll
            for (int n = 0; n < 4; ++n) acc[n] = (f32x4){0.f, 0.f, 0.f, 0.f};
            #pragma unroll
            for (int kk = 0; kk < 8; ++kk) {
                #pragma unroll
                for (int n = 0; n < 4; ++n)
                    acc[n] = __builtin_amdgcn_mfma_f32_16x16x32_bf16(A[kk], B[n][kk], acc[n], 0, 0, 0);
            }
            float pr[4] = {0.f, 0.f, 0.f, 0.f};
            #pragma unroll
            for (int n = 0; n < 4; ++n) {
                #pragma unroll
                for (int r = 0; r < 4; ++r) {
                    float h = fmaxf(acc[n][r] + b1r[n], 0.f);   // col=lane&15, row=lg*4+r
                    pr[r] = fmaf(h, w2r[n], pr[r]);
                }
            }
            #pragma unroll
            for (int r = 0; r < 4; ++r) pr[r] = red16(pr[r]);
            if (lr == 0) {
                const int er = mt * 16 + lg * 4;
                part[p][wn][er + 0] = pr[0];
                part[p][wn][er + 1] = pr[1];
                part[p][wn][er + 2] = pr[2];
                part[p][wn][er + 3] = pr[3];
            }
        }
    };

    // ---- persistent chunk loop (grid-stride NBLK) ----
    int c = blockIdx.x;
    if (c >= NCH) return;
    int p = 0;
    if (Z16) { stage_load(c); product_store(0); }
    else     { stage_f32(c, 0); }
    __syncthreads();

    while (true) {
        const int cn = c + NBLK;
        const bool hn = cn < NCH;
        if (Z16) {
            if (hn) stage_load(cn);       // gather latency hides under compute
            compute(p);
            if (hn) product_store(p ^ 1); // vmcnt drain + product + LDS write
        } else {
            compute(p);
            if (hn) stage_f32(cn, p ^ 1);
        }
        __syncthreads();
        if (t < 64) {                     // cross-wave N-reduce + bias + sigmoid
            float s = b2s + part[p][0][t] + part[p][1][t] + part[p][2][t] + part[p][3][t];
            out[c * 64 + t] = 1.f / (1.f + __expf(-s));
        }
        if (!hn) break;
        p ^= 1;
        c = cn;
    }
}

extern "C" void kernel_launch(void* const* d_in, const int* in_sizes, int n_in,
                              void* d_out, int out_size, void* d_ws, size_t ws_size,
                              hipStream_t stream) {
    const float* z  = (const float*)d_in[0];
    const int* src  = (const int*)d_in[1];
    const int* dst  = (const int*)d_in[2];
    const float* W1 = (const float*)d_in[3];
    const float* b1 = (const float*)d_in[4];
    const float* W2 = (const float*)d_in[5];
    const float* b2 = (const float*)d_in[6];
    float* out = (float*)d_out;

    const size_t z16_bytes = (size_t)NN * 256 * 2;   // 51.2 MB
    const size_t w1t_bytes = 256 * 256 * 2;          // 128 KB
    const bool use_z16 = ws_size >= z16_bytes + w1t_bytes;

    unsigned short* z16 = (unsigned short*)d_ws;
    unsigned short* w1t = use_z16 ? (unsigned short*)((char*)d_ws + z16_bytes)
                                  : (unsigned short*)d_ws;

    k_w1t<<<256, 256, 0, stream>>>(W1, w1t);
    if (use_z16) {
        k_zconv<<<12500, 256, 0, stream>>>(z, z16);
        k_main<true><<<NBLK, 512, 0, stream>>>(z, z16, src, dst, w1t, b1, W2, b2, out);
    } else {
        k_main<false><<<NBLK, 512, 0, stream>>>(z, (const unsigned short*)nullptr,
                                                src, dst, w1t, b1, W2, b2, out);
    }
}

// Round 5
// 342.396 us; speedup vs baseline: 3.6531x; 3.6531x over previous
//
#include <hip/hip_runtime.h>
#include <hip/hip_bf16.h>

#define NN 100000
#define EE 1000000
#define EPC 32             // edges per chunk
#define NCH 31250          // EE / EPC exactly
#define NBLK 512           // 2 independent 256-thread blocks per CU

typedef short bf16x8 __attribute__((ext_vector_type(8)));
typedef float f32x4 __attribute__((ext_vector_type(4)));

__device__ __forceinline__ unsigned short f2bf_rne(float f) {
    unsigned int u = __builtin_bit_cast(unsigned int, f);
    u = u + 0x7fffu + ((u >> 16) & 1u);
    return (unsigned short)(u >> 16);
}

// product of two bf16 pairs (packed dwords) -> bf16 pair (truncation)
__device__ __forceinline__ unsigned int bfprod2(unsigned int a, unsigned int b) {
    float alo = __builtin_bit_cast(float, a << 16);
    float ahi = __builtin_bit_cast(float, a & 0xffff0000u);
    float blo = __builtin_bit_cast(float, b << 16);
    float bhi = __builtin_bit_cast(float, b & 0xffff0000u);
    unsigned int lo = __builtin_bit_cast(unsigned int, alo * blo);
    unsigned int hi = __builtin_bit_cast(unsigned int, ahi * bhi);
    return __builtin_amdgcn_perm(hi, lo, 0x07060302u);
}

__device__ __forceinline__ unsigned int packtrunc(float lo, float hi) {
    return __builtin_amdgcn_perm(__builtin_bit_cast(unsigned int, hi),
                                 __builtin_bit_cast(unsigned int, lo), 0x07060302u);
}

template<int CTRL>
__device__ __forceinline__ float dpp_add(float v) {
    int s = __builtin_bit_cast(int, v);
    int m = __builtin_amdgcn_mov_dpp(s, CTRL, 0xF, 0xF, true);
    return v + __builtin_bit_cast(float, m);
}
__device__ __forceinline__ float red16(float v) {   // sum over 16-lane row (VALU pipe)
    v = dpp_add<0xB1>(v);
    v = dpp_add<0x4E>(v);
    v = dpp_add<0x124>(v);
    v = dpp_add<0x128>(v);
    return v;
}

// W1 [k][c] f32 -> W1T [c][k] bf16
__global__ void k_w1t(const float* __restrict__ W1, unsigned short* __restrict__ w1t) {
    int c = blockIdx.x, k = threadIdx.x;
    w1t[c * 256 + k] = f2bf_rne(W1[k * 256 + c]);
}

__global__ void k_zconv(const float* __restrict__ z, unsigned short* __restrict__ z16) {
    long long i = ((long long)blockIdx.x * 256 + threadIdx.x) * 8;
    float4 a = *(const float4*)(z + i);
    float4 b = *(const float4*)(z + i + 4);
    uint4 o;
    o.x = (unsigned)f2bf_rne(a.x) | ((unsigned)f2bf_rne(a.y) << 16);
    o.y = (unsigned)f2bf_rne(a.z) | ((unsigned)f2bf_rne(a.w) << 16);
    o.z = (unsigned)f2bf_rne(b.x) | ((unsigned)f2bf_rne(b.y) << 16);
    o.w = (unsigned)f2bf_rne(b.z) | ((unsigned)f2bf_rne(b.w) << 16);
    *(uint4*)(z16 + i) = o;
}

// Persistent fused kernel: 512 blocks (2 independent per CU) x 256 threads
// (4 waves, each owns 64 W1T cols, full K, pinned in regs/AGPRs).
// 32 edges per chunk. x tile in LDS in MFMA A-fragment order:
//   frag(mt,kk) base = (mt*8+kk)*1024; data for lane-position pos at slot
//   pos^kk (16B units) -> reads conflict-free (verified r4: conflicts = 0),
//   writes 2-way balanced (free).
// launch_bounds(256,2): cap 256 regs/wave (same environment that held B
// resident in r3) while guaranteeing 2 blocks/CU.
template<bool Z16>
__global__ __launch_bounds__(256, 2)
void k_main(const float* __restrict__ zf,
            const unsigned short* __restrict__ z16,
            const int* __restrict__ src, const int* __restrict__ dst,
            const unsigned short* __restrict__ w1t,
            const float* __restrict__ b1, const float* __restrict__ w2,
            const float* __restrict__ b2p, float* __restrict__ out)
{
    __shared__ __align__(16) char xs[2][16 * 1024];    // 2 x 16 KB frag buffers
    __shared__ float part[2][4][32];                   // 1 KB

    const int t = threadIdx.x;
    const int lane = t & 63;
    const int wn = t >> 6;                  // 4 waves = 4 N-quarters
    const int lr = lane & 15, lg = lane >> 4;

    // ---- B: wave's 64 W1T cols, full K=256, resident for the whole kernel ----
    bf16x8 B[4][8];
    float b1r[4], w2r[4];
    #pragma unroll
    for (int n = 0; n < 4; ++n) {
        const int col = wn * 64 + n * 16 + lr;
        const short* rp = (const short*)w1t + col * 256 + lg * 8;
        #pragma unroll
        for (int kk = 0; kk < 8; ++kk)
            B[n][kk] = *(const bf16x8*)(rp + kk * 32);
        b1r[n] = b1[col];
        w2r[n] = w2[col];
    }
    // pin: forbid sinking/rematerializing the B loads into the loop
    #pragma unroll
    for (int n = 0; n < 4; ++n)
        #pragma unroll
        for (int kk = 0; kk < 8; ++kk)
            asm volatile("" : "+v"(B[n][kk]));

    const float b2s = b2p[0];
    const int el = t >> 3, q = t & 7;       // 8 threads/edge, 32 ch each (coalesced)
    const int mtw = el >> 4, lrw = el & 15; // writer frag coords

    uint4 ga[4], gb[4];                     // in-flight gather regs (bf16 path)
    int sn, dn;                             // prefetched indices for next gather

    auto idx_load = [&](int c) { sn = src[c * EPC + el]; dn = dst[c * EPC + el]; };
    auto gather = [&](int s, int d) {       // issue gathers; consumed in product_store
        const uint4* sp = (const uint4*)(z16 + s * 256 + q * 32);
        const uint4* dp = (const uint4*)(z16 + d * 256 + q * 32);
        ga[0] = sp[0]; ga[1] = sp[1]; ga[2] = sp[2]; ga[3] = sp[3];
        gb[0] = dp[0]; gb[1] = dp[1]; gb[2] = dp[2]; gb[3] = dp[3];
    };
    auto product_store = [&](int p) {
        char* fb = xs[p] + (mtw * 8 + q) * 1024;
        #pragma unroll
        for (int i = 0; i < 4; ++i) {
            uint4 x;
            x.x = bfprod2(ga[i].x, gb[i].x);
            x.y = bfprod2(ga[i].y, gb[i].y);
            x.z = bfprod2(ga[i].z, gb[i].z);
            x.w = bfprod2(ga[i].w, gb[i].w);
            *(uint4*)(fb + (((i * 16 + lrw) ^ q) * 16)) = x;
        }
    };
    auto stage_f32 = [&](int c, int p) {    // f32 fallback: load+product+store
        const int e = c * EPC + el;
        const int s = src[e], d = dst[e];
        const float4* sp = (const float4*)(zf + s * 256 + q * 32);
        const float4* dp = (const float4*)(zf + d * 256 + q * 32);
        char* fb = xs[p] + (mtw * 8 + q) * 1024;
        #pragma unroll
        for (int i = 0; i < 4; ++i) {
            float4 a0 = sp[2 * i], a1 = sp[2 * i + 1];
            float4 c0 = dp[2 * i], c1 = dp[2 * i + 1];
            uint4 x;
            x.x = packtrunc(a0.x * c0.x, a0.y * c0.y);
            x.y = packtrunc(a0.z * c0.z, a0.w * c0.w);
            x.z = packtrunc(a1.x * c1.x, a1.y * c1.y);
            x.w = packtrunc(a1.z * c1.z, a1.w * c1.w);
            *(uint4*)(fb + (((i * 16 + lrw) ^ q) * 16)) = x;
        }
    };
    auto compute = [&](int p) {
        #pragma unroll
        for (int mt = 0; mt < 2; ++mt) {
            const char* fp = xs[p] + mt * 8192;
            bf16x8 A[8];
            #pragma unroll
            for (int kk = 0; kk < 8; ++kk)
                A[kk] = *(const bf16x8*)(fp + kk * 1024 + ((lane ^ kk) * 16));
            f32x4 acc[4];
            #pragma unroll
            for (int n = 0; n < 4; ++n) acc[n] = (f32x4){0.f, 0.f, 0.f, 0.f};
            #pragma unroll
            for (int kk = 0; kk < 8; ++kk) {
                #pragma unroll
                for (int n = 0; n < 4; ++n)
                    acc[n] = __builtin_amdgcn_mfma_f32_16x16x32_bf16(A[kk], B[n][kk], acc[n], 0, 0, 0);
            }
            float pr[4] = {0.f, 0.f, 0.f, 0.f};
            #pragma unroll
            for (int n = 0; n < 4; ++n) {
                #pragma unroll
                for (int r = 0; r < 4; ++r) {
                    float h = fmaxf(acc[n][r] + b1r[n], 0.f);   // col=lane&15, row=lg*4+r
                    pr[r] = fmaf(h, w2r[n], pr[r]);
                }
            }
            #pragma unroll
            for (int r = 0; r < 4; ++r) pr[r] = red16(pr[r]);
            if (lr == 0) {
                const int er = mt * 16 + lg * 4;
                part[p][wn][er + 0] = pr[0];
                part[p][wn][er + 1] = pr[1];
                part[p][wn][er + 2] = pr[2];
                part[p][wn][er + 3] = pr[3];
            }
        }
    };

    // ---- persistent chunk loop (grid-stride NBLK), 2-deep idx prefetch ----
    int c = blockIdx.x;
    int p = 0;
    if (Z16) {
        idx_load(c);
        gather(sn, dn);
        if (c + NBLK < NCH) idx_load(c + NBLK);   // prefetch next chunk's indices
        product_store(0);
    } else {
        stage_f32(c, 0);
    }
    __syncthreads();

    while (true) {
        const int cn = c + NBLK;
        const bool hn = cn < NCH;
        if (Z16) {
            if (hn) {
                gather(sn, dn);                    // idx already resident
                if (cn + NBLK < NCH) idx_load(cn + NBLK);
            }
            compute(p);
            if (hn) product_store(p ^ 1);          // vmcnt drain + product + LDS write
        } else {
            compute(p);
            if (hn) stage_f32(cn, p ^ 1);
        }
        __syncthreads();
        if (t < EPC) {                             // cross-wave N-reduce + sigmoid
            float s = b2s + part[p][0][t] + part[p][1][t] + part[p][2][t] + part[p][3][t];
            out[c * EPC + t] = 1.f / (1.f + __expf(-s));
        }
        if (!hn) break;
        p ^= 1;
        c = cn;
    }
}

extern "C" void kernel_launch(void* const* d_in, const int* in_sizes, int n_in,
                              void* d_out, int out_size, void* d_ws, size_t ws_size,
                              hipStream_t stream) {
    const float* z  = (const float*)d_in[0];
    const int* src  = (const int*)d_in[1];
    const int* dst  = (const int*)d_in[2];
    const float* W1 = (const float*)d_in[3];
    const float* b1 = (const float*)d_in[4];
    const float* W2 = (const float*)d_in[5];
    const float* b2 = (const float*)d_in[6];
    float* out = (float*)d_out;

    const size_t z16_bytes = (size_t)NN * 256 * 2;   // 51.2 MB
    const size_t w1t_bytes = 256 * 256 * 2;          // 128 KB
    const bool use_z16 = ws_size >= z16_bytes + w1t_bytes;

    unsigned short* z16 = (unsigned short*)d_ws;
    unsigned short* w1t = use_z16 ? (unsigned short*)((char*)d_ws + z16_bytes)
                                  : (unsigned short*)d_ws;

    k_w1t<<<256, 256, 0, stream>>>(W1, w1t);
    if (use_z16) {
        k_zconv<<<12500, 256, 0, stream>>>(z, z16);
        k_main<true><<<NBLK, 256, 0, stream>>>(z, z16, src, dst, w1t, b1, W2, b2, out);
    } else {
        k_main<false><<<NBLK, 256, 0, stream>>>(z, (const unsigned short*)nullptr,
                                                src, dst, w1t, b1, W2, b2, out);
    }
}

// Round 9
// 314.252 us; speedup vs baseline: 3.9802x; 1.0896x over previous
//
#include <hip/hip_runtime.h>
#include <hip/hip_fp16.h>

#define NN 100000
#define EE 1000000
#define EPC 32             // edges per chunk
#define NCH 31250          // EE / EPC exactly
#define NBLK 512           // 2 independent 256-thread blocks per CU
#define ZBLK 12500         // zconv blocks: 25.6e6 elems / 8 / 256

typedef _Float16 f16x8 __attribute__((ext_vector_type(8)));
typedef _Float16 f16x2 __attribute__((ext_vector_type(2)));
typedef __fp16 fp16x2 __attribute__((ext_vector_type(2)));   // builtin return type
typedef float f32x4 __attribute__((ext_vector_type(4)));

// packed fp16 multiply: 1 x v_pk_mul_f16 per dword (2 channels)
__device__ __forceinline__ unsigned int pkmul(unsigned int a, unsigned int b) {
    f16x2 x = __builtin_bit_cast(f16x2, a);
    f16x2 y = __builtin_bit_cast(f16x2, b);
    f16x2 r = x * y;
    return __builtin_bit_cast(unsigned int, r);
}
// pack two f32 -> fp16 pair (RTZ, 1 inst)
__device__ __forceinline__ unsigned int pkcvt(float lo, float hi) {
    fp16x2 r = __builtin_amdgcn_cvt_pkrtz(lo, hi);
    return __builtin_bit_cast(unsigned int, r);
}

template<int CTRL>
__device__ __forceinline__ float dpp_add(float v) {
    int s = __builtin_bit_cast(int, v);
    int m = __builtin_amdgcn_mov_dpp(s, CTRL, 0xF, 0xF, true);
    return v + __builtin_bit_cast(float, m);
}
__device__ __forceinline__ float red16(float v) {   // sum over 16-lane row (VALU pipe)
    v = dpp_add<0xB1>(v);
    v = dpp_add<0x4E>(v);
    v = dpp_add<0x124>(v);
    v = dpp_add<0x128>(v);
    return v;
}

// Merged prologue: blocks [0,ZBLK) convert z f32->fp16 (8 elems/thread);
// blocks [ZBLK, ZBLK+256) transpose+convert W1 -> W1T [c][k] fp16.
__global__ void k_prep(const float* __restrict__ z, const float* __restrict__ W1,
                       unsigned short* __restrict__ zh, unsigned short* __restrict__ w1t) {
    const int b = blockIdx.x;
    if (b < ZBLK) {
        long long i = ((long long)b * 256 + threadIdx.x) * 8;
        float4 a = *(const float4*)(z + i);
        float4 c = *(const float4*)(z + i + 4);
        uint4 o;
        o.x = pkcvt(a.x, a.y);
        o.y = pkcvt(a.z, a.w);
        o.z = pkcvt(c.x, c.y);
        o.w = pkcvt(c.z, c.w);
        *(uint4*)(zh + i) = o;
    } else {
        const int c = b - ZBLK, k = threadIdx.x;
        _Float16 h = (_Float16)W1[k * 256 + c];   // RNE scalar convert
        w1t[c * 256 + k] = __builtin_bit_cast(unsigned short, h);
    }
}

// Persistent fused kernel: 512 blocks (2 independent per CU) x 256 threads
// (4 waves, each owns 64 W1T cols, full K=256, pinned in regs).
// 32 edges/chunk. x tile in LDS in MFMA A-fragment order:
//   frag(mt,kk) base=(mt*8+kk)*1024; lane-position pos stored at slot pos^kk
//   (16B units) -> reads conflict-free (measured r4/r5: SQ_LDS_BANK_CONFLICT=0),
//   writes 2-way balanced (free per m136).
template<bool ZH>
__global__ __launch_bounds__(256, 2)
void k_main(const float* __restrict__ zf,
            const unsigned short* __restrict__ zh,
            const int* __restrict__ src, const int* __restrict__ dst,
            const unsigned short* __restrict__ w1t,
            const float* __restrict__ b1, const float* __restrict__ w2,
            const float* __restrict__ b2p, float* __restrict__ out)
{
    __shared__ __align__(16) char xs[2][16 * 1024];    // 2 x 16 KB frag buffers
    __shared__ float part[2][4][32];                   // 1 KB

    const int t = threadIdx.x;
    const int lane = t & 63;
    const int wn = t >> 6;                  // 4 waves = 4 N-quarters
    const int lr = lane & 15, lg = lane >> 4;

    // ---- B: wave's 64 W1T cols, full K=256, resident for the whole kernel ----
    f16x8 B[4][8];
    float b1r[4], w2r[4];
    #pragma unroll
    for (int n = 0; n < 4; ++n) {
        const int col = wn * 64 + n * 16 + lr;
        const short* rp = (const short*)w1t + col * 256 + lg * 8;
        #pragma unroll
        for (int kk = 0; kk < 8; ++kk)
            B[n][kk] = *(const f16x8*)(rp + kk * 32);
        b1r[n] = b1[col];
        w2r[n] = w2[col];
    }
    // pin: forbid sinking/rematerializing the B loads into the loop
    #pragma unroll
    for (int n = 0; n < 4; ++n)
        #pragma unroll
        for (int kk = 0; kk < 8; ++kk)
            asm volatile("" : "+v"(B[n][kk]));

    const float b2s = b2p[0];
    const int el = t >> 3, q = t & 7;       // 8 threads/edge, 32 ch each (coalesced)
    const int mtw = el >> 4, lrw = el & 15; // writer frag coords

    uint4 ga[4], gb[4];                     // in-flight gather regs (fp16 path)
    int sn, dn;                             // prefetched indices for next gather

    auto idx_load = [&](int c) { sn = src[c * EPC + el]; dn = dst[c * EPC + el]; };
    auto gather = [&](int s, int d) {       // issue gathers; consumed in product_store
        const uint4* sp = (const uint4*)(zh + s * 256 + q * 32);
        const uint4* dp = (const uint4*)(zh + d * 256 + q * 32);
        ga[0] = sp[0]; ga[1] = sp[1]; ga[2] = sp[2]; ga[3] = sp[3];
        gb[0] = dp[0]; gb[1] = dp[1]; gb[2] = dp[2]; gb[3] = dp[3];
    };
    auto product_store = [&](int p) {
        char* fb = xs[p] + (mtw * 8 + q) * 1024;
        #pragma unroll
        for (int i = 0; i < 4; ++i) {
            uint4 x;
            x.x = pkmul(ga[i].x, gb[i].x);
            x.y = pkmul(ga[i].y, gb[i].y);
            x.z = pkmul(ga[i].z, gb[i].z);
            x.w = pkmul(ga[i].w, gb[i].w);
            *(uint4*)(fb + (((i * 16 + lrw) ^ q) * 16)) = x;
        }
    };
    auto stage_f32 = [&](int c, int p) {    // f32 fallback: load+product+cvt+store
        const int e = c * EPC + el;
        const int s = src[e], d = dst[e];
        const float4* sp = (const float4*)(zf + s * 256 + q * 32);
        const float4* dp = (const float4*)(zf + d * 256 + q * 32);
        char* fb = xs[p] + (mtw * 8 + q) * 1024;
        #pragma unroll
        for (int i = 0; i < 4; ++i) {
            float4 a0 = sp[2 * i], a1 = sp[2 * i + 1];
            float4 c0 = dp[2 * i], c1 = dp[2 * i + 1];
            uint4 x;
            x.x = pkcvt(a0.x * c0.x, a0.y * c0.y);
            x.y = pkcvt(a0.z * c0.z, a0.w * c0.w);
            x.z = pkcvt(a1.x * c1.x, a1.y * c1.y);
            x.w = pkcvt(a1.z * c1.z, a1.w * c1.w);
            *(uint4*)(fb + (((i * 16 + lrw) ^ q) * 16)) = x;
        }
    };
    auto compute = [&](int p) {
        #pragma unroll
        for (int mt = 0; mt < 2; ++mt) {
            const char* fp = xs[p] + mt * 8192;
            f16x8 A[8];
            #pragma unroll
            for (int kk = 0; kk < 8; ++kk)
                A[kk] = *(const f16x8*)(fp + kk * 1024 + ((lane ^ kk) * 16));
            f32x4 acc[4];
            #pragma unroll
            for (int n = 0; n < 4; ++n) acc[n] = (f32x4){0.f, 0.f, 0.f, 0.f};
            #pragma unroll
            for (int kk = 0; kk < 8; ++kk) {
                #pragma unroll
                for (int n = 0; n < 4; ++n)
                    acc[n] = __builtin_amdgcn_mfma_f32_16x16x32_f16(A[kk], B[n][kk], acc[n], 0, 0, 0);
            }
            float pr[4] = {0.f, 0.f, 0.f, 0.f};
            #pragma unroll
            for (int n = 0; n < 4; ++n) {
                #pragma unroll
                for (int r = 0; r < 4; ++r) {
                    float h = fmaxf(acc[n][r] + b1r[n], 0.f);   // col=lane&15, row=lg*4+r
                    pr[r] = fmaf(h, w2r[n], pr[r]);
                }
            }
            #pragma unroll
            for (int r = 0; r < 4; ++r) pr[r] = red16(pr[r]);
            if (lr == 0) {
                const int er = mt * 16 + lg * 4;
                part[p][wn][er + 0] = pr[0];
                part[p][wn][er + 1] = pr[1];
                part[p][wn][er + 2] = pr[2];
                part[p][wn][er + 3] = pr[3];
            }
        }
    };

    // ---- persistent chunk loop (grid-stride NBLK), 2-deep idx prefetch ----
    int c = blockIdx.x;
    int p = 0;
    if (ZH) {
        idx_load(c);
        gather(sn, dn);
        if (c + NBLK < NCH) idx_load(c + NBLK);   // prefetch next chunk's indices
        product_store(0);
    } else {
        stage_f32(c, 0);
    }
    __syncthreads();

    while (true) {
        const int cn = c + NBLK;
        const bool hn = cn < NCH;
        if (ZH) {
            if (hn) {
                gather(sn, dn);                    // idx already resident
                if (cn + NBLK < NCH) idx_load(cn + NBLK);
            }
            compute(p);
            if (hn) product_store(p ^ 1);          // vmcnt drain + product + LDS write
        } else {
            compute(p);
            if (hn) stage_f32(cn, p ^ 1);
        }
        __syncthreads();
        if (t < EPC) {                             // cross-wave N-reduce + sigmoid
            float s = b2s + part[p][0][t] + part[p][1][t] + part[p][2][t] + part[p][3][t];
            out[c * EPC + t] = 1.f / (1.f + __expf(-s));
        }
        if (!hn) break;
        p ^= 1;
        c = cn;
    }
}

extern "C" void kernel_launch(void* const* d_in, const int* in_sizes, int n_in,
                              void* d_out, int out_size, void* d_ws, size_t ws_size,
                              hipStream_t stream) {
    const float* z  = (const float*)d_in[0];
    const int* src  = (const int*)d_in[1];
    const int* dst  = (const int*)d_in[2];
    const float* W1 = (const float*)d_in[3];
    const float* b1 = (const float*)d_in[4];
    const float* W2 = (const float*)d_in[5];
    const float* b2 = (const float*)d_in[6];
    float* out = (float*)d_out;

    const size_t zh_bytes  = (size_t)NN * 256 * 2;   // 51.2 MB
    const size_t w1t_bytes = 256 * 256 * 2;          // 128 KB
    const bool use_zh = ws_size >= zh_bytes + w1t_bytes;

    unsigned short* zh  = (unsigned short*)d_ws;
    unsigned short* w1t = use_zh ? (unsigned short*)((char*)d_ws + zh_bytes)
                                 : (unsigned short*)d_ws;

    if (use_zh) {
        k_prep<<<ZBLK + 256, 256, 0, stream>>>(z, W1, zh, w1t);
        k_main<true><<<NBLK, 256, 0, stream>>>(z, zh, src, dst, w1t, b1, W2, b2, out);
    } else {
        // ws too small for zh: still need w1t (128 KB) — reuse k_prep's tail only.
        k_prep<<<ZBLK + 256, 256, 0, stream>>>(z, W1, (unsigned short*)d_ws, w1t); // zh unused
        k_main<false><<<NBLK, 256, 0, stream>>>(z, (const unsigned short*)nullptr,
                                                src, dst, w1t, b1, W2, b2, out);
    }
}